// Round 5
// baseline (146.806 us; speedup 1.0000x reference)
//
#include <hip/hip_runtime.h>
#include <math.h>

#define NBATCH 128
#define NP 256
#define NC 64
#define KNN 16
#define EPSV 1e-3f
#define INF32 3.0e38f

typedef __bf16 bf16_t;
typedef bf16_t bf16x8 __attribute__((ext_vector_type(8)));
typedef float f32x4 __attribute__((ext_vector_type(4)));

static __device__ __forceinline__ f32x4 mfma16(bf16x8 a, bf16x8 b, f32x4 c) {
    return __builtin_amdgcn_mfma_f32_16x16x32_bf16(a, b, c, 0, 0, 0);
}
static __device__ __forceinline__ unsigned short f2bfu(float f) {
    union { bf16_t b; unsigned short u; } cv; cv.b = (bf16_t)f; return cv.u;
}
static __device__ __forceinline__ bf16x8 pack8(float4 a, float4 b) {
    bf16x8 r;
    r[0] = (bf16_t)a.x; r[1] = (bf16_t)a.y; r[2] = (bf16_t)a.z; r[3] = (bf16_t)a.w;
    r[4] = (bf16_t)b.x; r[5] = (bf16_t)b.y; r[6] = (bf16_t)b.z; r[7] = (bf16_t)b.w;
    return r;
}
// wave-private LDS ordering fence (rule #18: asm waitcnt needs sched_barrier)
#define LDS_FENCE() do { asm volatile("s_waitcnt lgkmcnt(0)" ::: "memory"); \
                         __builtin_amdgcn_sched_barrier(0); } while (0)

// 16-level predicated sorted insertion on packed u32 keys
// key = (float_bits(d) & 0xFFFFFF00) | idx  -> total order, low idx wins ties
#define INSERTK(k_)                                                   \
    do {                                                              \
        _Pragma("unroll")                                             \
        for (int ii = KNN - 1; ii >= 1; --ii) {                       \
            const bool wr = (k_) < bk[ii];                            \
            const bool sh = (k_) < bk[ii - 1];                        \
            const unsigned nv = sh ? bk[ii - 1] : (k_);               \
            if (wr) bk[ii] = nv;                                      \
        }                                                             \
        if ((k_) < bk[0]) bk[0] = (k_);                               \
    } while (0)

// ---------------------------------------------------------------------------
// kNN v3: packed u32 (dist|idx) keys, f32 cancellation-free distances,
// 2-way candidate split; merge via LDS. Grid = 2*NBATCH blocks of 256 thr.
// ---------------------------------------------------------------------------
__global__ __launch_bounds__(256) void knn_kernel(const float* __restrict__ points,
                                                  int* __restrict__ idx_out) {
    const int bb = blockIdx.x >> 1;
    const int qbase = (blockIdx.x & 1) * 128;
    const int t = threadIdx.x;
    const int qt = t & 127;
    const int half = t >> 7;
    const int p = qbase + qt;            // my query (within batch)

    __shared__ __align__(16) float4 sp[NP];
    __shared__ unsigned sk[128][17];

    const float* pb = points + (size_t)bb * NP * 3;
    sp[t] = make_float4(pb[t * 3 + 0], pb[t * 3 + 1], pb[t * 3 + 2], 0.f);
    __syncthreads();

    const float4 qp = sp[p];
    unsigned bk[KNN];
#pragma unroll
    for (int i = 0; i < KNN; ++i) bk[i] = 0xFFFFFFFFu;

    const int cbase = half * 128;        // wave-uniform
#pragma unroll 4
    for (int c = 0; c < 128; ++c) {
        const int cand = cbase + c;
        const float4 P = sp[cand];       // wave-uniform addr -> LDS broadcast
        const float dx = qp.x - P.x, dy = qp.y - P.y, dz = qp.z - P.z;
        const float d = fmaf(dx, dx, fmaf(dy, dy, dz * dz));
        unsigned key = (__float_as_uint(d) & 0xFFFFFF00u) | (unsigned)cand;
        key = (cand == p) ? 0xFFFFFFFFu : key;   // self-exclusion, branchless
        INSERTK(key);
    }

    if (half == 1) {
#pragma unroll
        for (int i = 0; i < KNN; ++i) sk[qt][i] = bk[i];
    }
    __syncthreads();
    if (half == 0) {
        for (int j = 0; j < KNN; ++j) {
            const unsigned key = sk[qt][j];
            if (key >= bk[KNN - 1]) break;   // ascending -> rest can't qualify
            INSERTK(key);
        }
        int* op = idx_out + ((size_t)bb * NP + p) * KNN;
#pragma unroll
        for (int i = 0; i < KNN; ++i) op[i] = (int)(bk[i] & 0xFFu);
    }
}

// ---------------------------------------------------------------------------
// Prep (unchanged): lay out weights in MFMA B-fragment order + fold BN params.
// B-frag (16x16x32): lane l holds B[ks*32 + (l>>4)*8 + j][t*16 + (l&15)].
// ---------------------------------------------------------------------------
__global__ __launch_bounds__(256) void prep_kernel(
    const float* __restrict__ w0, const float* __restrict__ w1,
    const float* __restrict__ w2, const float* __restrict__ sc_w,
    const float* __restrict__ gammas, const float* __restrict__ betas,
    const float* __restrict__ means, const float* __restrict__ variances,
    const float* __restrict__ sc_gamma, const float* __restrict__ sc_beta,
    const float* __restrict__ sc_mean, const float* __restrict__ sc_var,
    unsigned short* __restrict__ wsf, float* __restrict__ bnp)
{
    const int tid = blockIdx.x * 256 + threadIdx.x;
    if (tid < 20480) {
        const float* src;
        int base;
        if (tid < 8192)       { src = w0;   base = 0; }
        else if (tid < 12288) { src = w1;   base = 8192; }
        else if (tid < 16384) { src = w2;   base = 12288; }
        else                  { src = sc_w; base = 16384; }
        const int e2 = tid - base;
        const int f = e2 >> 9;
        const int r = e2 & 511;
        const int lane = r >> 3, j = r & 7;
        const int ks = f >> 2, t = f & 3;
        const int row = ks * 32 + (lane >> 4) * 8 + j;
        const int col = t * 16 + (lane & 15);
        wsf[tid] = f2bfu(src[row * 64 + col]);
    } else {
        const int e = tid - 20480;
        if (e < 192) {
            float s = gammas[e] * rsqrtf(variances[e] + EPSV);
            bnp[e] = s;
            bnp[192 + e] = betas[e] - means[e] * s;
        } else if (e < 256) {
            const int d = e - 192;
            float s = sc_gamma[d] * rsqrtf(sc_var[d] + EPSV);
            bnp[384 + d] = s;
            bnp[448 + d] = sc_beta[d] - sc_mean[d] * s;
        }
    }
}

// ---------------------------------------------------------------------------
// Edge MLP on matrix cores. One wave per block; wave owns 8 points (was 16)
// -> 4096 blocks = 16 waves/CU for latency hiding. XCD-swizzled blockIdx so
// each batch's 32 blocks share one XCD's L2 (features slice = 64 KB resident).
// Neighbor indices preloaded; shortcut GEMM moved post-loop (lower reg peak).
// ---------------------------------------------------------------------------
__global__ __launch_bounds__(64, 4) void edge_kernel(
    const float* __restrict__ features, const int* __restrict__ knn_idx,
    const unsigned short* __restrict__ wsf, const float* __restrict__ bnp,
    float* __restrict__ out)
{
    __shared__ __align__(16) unsigned short slabA[16 * 72];  // row stride 144 B
    __shared__ __align__(16) unsigned short slabB[16 * 72];
    __shared__ float ftsbuf[8][64];   // [point q][channel]

    const int l = threadIdx.x;
    const int i = l & 15;
    const int h = l >> 4;
    // bijective XCD swizzle: 4096 blocks = 8 XCDs x 512 contiguous work items
    const int wg = (blockIdx.x & 7) * 512 + (blockIdx.x >> 3);
    const int p0 = wg * 8;
    const int b = p0 >> 8;

    const bf16x8* __restrict__ W0 = (const bf16x8*)(wsf);
    const bf16x8* __restrict__ W1 = (const bf16x8*)(wsf + 8192);
    const bf16x8* __restrict__ W2 = (const bf16x8*)(wsf + 12288);

    // layer weights resident in registers for the whole wave lifetime
    bf16x8 w0r[4][4], w1r[2][4], w2r[2][4];
#pragma unroll
    for (int ks = 0; ks < 4; ++ks)
#pragma unroll
        for (int t = 0; t < 4; ++t) w0r[ks][t] = W0[(ks * 4 + t) * 64 + l];
#pragma unroll
    for (int ks = 0; ks < 2; ++ks)
#pragma unroll
        for (int t = 0; t < 4; ++t) {
            w1r[ks][t] = W1[(ks * 4 + t) * 64 + l];
            w2r[ks][t] = W2[(ks * 4 + t) * 64 + l];
        }

    float scl[3][4], shf[3][4];
#pragma unroll
    for (int L = 0; L < 3; ++L)
#pragma unroll
        for (int t = 0; t < 4; ++t) {
            scl[L][t] = bnp[L * 64 + t * 16 + i];
            shf[L][t] = bnp[192 + L * 64 + t * 16 + i];
        }

    // preload this wave's 8 neighbor indices (lane's k = i)
    int nks[8];
#pragma unroll
    for (int q = 0; q < 8; ++q) nks[q] = knn_idx[(size_t)(p0 + q) * KNN + i];

    for (int q = 0; q < 8; ++q) {
        const float* cp = features + (size_t)(p0 + q) * NC;
        const float* sp = features + (size_t)(b * NP + nks[q]) * NC;
        float4 c0 = *(const float4*)(cp + h * 8);
        float4 c1 = *(const float4*)(cp + h * 8 + 4);
        float4 c2 = *(const float4*)(cp + 32 + h * 8);
        float4 c3 = *(const float4*)(cp + 32 + h * 8 + 4);
        float4 n0 = *(const float4*)(sp + h * 8);
        float4 n1 = *(const float4*)(sp + h * 8 + 4);
        float4 n2 = *(const float4*)(sp + 32 + h * 8);
        float4 n3 = *(const float4*)(sp + 32 + h * 8 + 4);
        float4 d0, d1, d2, d3;
        d0.x = n0.x - c0.x; d0.y = n0.y - c0.y; d0.z = n0.z - c0.z; d0.w = n0.w - c0.w;
        d1.x = n1.x - c1.x; d1.y = n1.y - c1.y; d1.z = n1.z - c1.z; d1.w = n1.w - c1.w;
        d2.x = n2.x - c2.x; d2.y = n2.y - c2.y; d2.z = n2.z - c2.z; d2.w = n2.w - c2.w;
        d3.x = n3.x - c3.x; d3.y = n3.y - c3.y; d3.z = n3.z - c3.z; d3.w = n3.w - c3.w;
        bf16x8 fA[4];
        fA[0] = pack8(c0, c1);  // A cols 0..63  = center
        fA[1] = pack8(c2, c3);
        fA[2] = pack8(d0, d1);  // A cols 64..127 = nbr - center
        fA[3] = pack8(d2, d3);

        // ---- layer 1 -> slabA ----
#pragma unroll
        for (int t = 0; t < 4; ++t) {
            f32x4 acc = {0.f, 0.f, 0.f, 0.f};
#pragma unroll
            for (int ks = 0; ks < 4; ++ks) acc = mfma16(fA[ks], w0r[ks][t], acc);
#pragma unroll
            for (int r = 0; r < 4; ++r) {
                float y = fmaxf(fmaf(acc[r], scl[0][t], shf[0][t]), 0.f);
                slabA[(h * 4 + r) * 72 + t * 16 + i] = f2bfu(y);
            }
        }
        LDS_FENCE();

        // ---- layer 2 -> slabB ----
        bf16x8 a20 = *(const bf16x8*)(slabA + i * 72 + h * 8);
        bf16x8 a21 = *(const bf16x8*)(slabA + i * 72 + h * 8 + 32);
#pragma unroll
        for (int t = 0; t < 4; ++t) {
            f32x4 acc = {0.f, 0.f, 0.f, 0.f};
            acc = mfma16(a20, w1r[0][t], acc);
            acc = mfma16(a21, w1r[1][t], acc);
#pragma unroll
            for (int r = 0; r < 4; ++r) {
                float y = fmaxf(fmaf(acc[r], scl[1][t], shf[1][t]), 0.f);
                slabB[(h * 4 + r) * 72 + t * 16 + i] = f2bfu(y);
            }
        }
        LDS_FENCE();

        // ---- layer 3 -> fts (mean over k) ----
        bf16x8 a30 = *(const bf16x8*)(slabB + i * 72 + h * 8);
        bf16x8 a31 = *(const bf16x8*)(slabB + i * 72 + h * 8 + 32);
#pragma unroll
        for (int t = 0; t < 4; ++t) {
            f32x4 acc = {0.f, 0.f, 0.f, 0.f};
            acc = mfma16(a30, w2r[0][t], acc);
            acc = mfma16(a31, w2r[1][t], acc);
            float s = 0.f;
#pragma unroll
            for (int r = 0; r < 4; ++r)
                s += fmaxf(fmaf(acc[r], scl[2][t], shf[2][t]), 0.f);
            s += __shfl_xor(s, 16, 64);  // reduce over h-groups (same i)
            s += __shfl_xor(s, 32, 64);
            if (h == 0) ftsbuf[q][t * 16 + i] = s * (1.f / 16.f);
        }
        LDS_FENCE();  // covers slab WAR for next iter + ftsbuf visibility
    }

    // ---- shortcut GEMM + epilogue: rows 0..7 = this wave's 8 points ----
    {
        const bf16x8* __restrict__ WS = (const bf16x8*)(wsf + 16384);
        float sscl[4], sshf[4];
#pragma unroll
        for (int t = 0; t < 4; ++t) {
            sscl[t] = bnp[384 + t * 16 + i];
            sshf[t] = bnp[448 + t * 16 + i];
        }
        const float* fp = features + (size_t)(p0 + (i & 7)) * NC;  // rows 8..15 dup
        float4 c0 = *(const float4*)(fp + h * 8);
        float4 c1 = *(const float4*)(fp + h * 8 + 4);
        float4 c2 = *(const float4*)(fp + 32 + h * 8);
        float4 c3 = *(const float4*)(fp + 32 + h * 8 + 4);
        bf16x8 a0 = pack8(c0, c1), a1 = pack8(c2, c3);
#pragma unroll
        for (int t = 0; t < 4; ++t) {
            f32x4 acc = {0.f, 0.f, 0.f, 0.f};
            acc = mfma16(a0, WS[t * 64 + l], acc);
            acc = mfma16(a1, WS[(4 + t) * 64 + l], acc);
            if (h < 2) {   // C rows 0..7 = real points; 8..15 are duplicates
#pragma unroll
                for (int r = 0; r < 4; ++r) {
                    const int q = h * 4 + r;
                    out[(size_t)(p0 + q) * NC + t * 16 + i] =
                        fmaxf(fmaf(acc[r], sscl[t], sshf[t]) + ftsbuf[q][t * 16 + i], 0.f);
                }
            }
        }
    }
}

extern "C" void kernel_launch(void* const* d_in, const int* in_sizes, int n_in,
                              void* d_out, int out_size, void* d_ws, size_t ws_size,
                              hipStream_t stream) {
    const float* points    = (const float*)d_in[0];
    const float* features  = (const float*)d_in[1];
    const float* w0        = (const float*)d_in[2];
    const float* w1        = (const float*)d_in[3];
    const float* w2        = (const float*)d_in[4];
    const float* gammas    = (const float*)d_in[5];
    const float* betas     = (const float*)d_in[6];
    const float* means     = (const float*)d_in[7];
    const float* variances = (const float*)d_in[8];
    const float* sc_w      = (const float*)d_in[9];
    const float* sc_gamma  = (const float*)d_in[10];
    const float* sc_beta   = (const float*)d_in[11];
    const float* sc_mean   = (const float*)d_in[12];
    const float* sc_var    = (const float*)d_in[13];
    float* out = (float*)d_out;

    int* knn_buf = (int*)d_ws;                                        // 2 MB
    unsigned short* wsf = (unsigned short*)((char*)d_ws + (1 << 21)); // 40 KB
    float* bnp = (float*)((char*)d_ws + (1 << 21) + 40960);           // 1.8 KB

    prep_kernel<<<81, 256, 0, stream>>>(w0, w1, w2, sc_w, gammas, betas, means,
                                        variances, sc_gamma, sc_beta, sc_mean,
                                        sc_var, wsf, bnp);
    knn_kernel<<<NBATCH * 2, 256, 0, stream>>>(points, knn_buf);
    edge_kernel<<<NBATCH * NP / 8, 64, 0, stream>>>(features, knn_buf, wsf, bnp, out);
}

// Round 6
// 67.720 us; speedup vs baseline: 2.1678x; 2.1678x over previous
//
#include <hip/hip_runtime.h>
#include <math.h>

#define NBATCH 128
#define NP 256
#define NC 64
#define KNN 16
#define EPSV 1e-3f
#define INF32 3.0e38f

typedef __bf16 bf16_t;
typedef bf16_t bf16x8 __attribute__((ext_vector_type(8)));
typedef float f32x4 __attribute__((ext_vector_type(4)));

static __device__ __forceinline__ f32x4 mfma16(bf16x8 a, bf16x8 b, f32x4 c) {
    return __builtin_amdgcn_mfma_f32_16x16x32_bf16(a, b, c, 0, 0, 0);
}
static __device__ __forceinline__ unsigned short f2bfu(float f) {
    union { bf16_t b; unsigned short u; } cv; cv.b = (bf16_t)f; return cv.u;
}
static __device__ __forceinline__ bf16x8 pack8(float4 a, float4 b) {
    bf16x8 r;
    r[0] = (bf16_t)a.x; r[1] = (bf16_t)a.y; r[2] = (bf16_t)a.z; r[3] = (bf16_t)a.w;
    r[4] = (bf16_t)b.x; r[5] = (bf16_t)b.y; r[6] = (bf16_t)b.z; r[7] = (bf16_t)b.w;
    return r;
}
// wave-private LDS ordering fence (rule #18: asm waitcnt needs sched_barrier)
#define LDS_FENCE() do { asm volatile("s_waitcnt lgkmcnt(0)" ::: "memory"); \
                         __builtin_amdgcn_sched_barrier(0); } while (0)

// 16-level predicated sorted insertion on packed u32 keys
// key = (float_bits(d) & 0xFFFFFF00) | idx  -> total order, low idx wins ties
#define INSERTK(k_)                                                   \
    do {                                                              \
        _Pragma("unroll")                                             \
        for (int ii = KNN - 1; ii >= 1; --ii) {                       \
            const bool wr = (k_) < bk[ii];                            \
            const bool sh = (k_) < bk[ii - 1];                        \
            const unsigned nv = sh ? bk[ii - 1] : (k_);               \
            if (wr) bk[ii] = nv;                                      \
        }                                                             \
        if ((k_) < bk[0]) bk[0] = (k_);                               \
    } while (0)

// ---------------------------------------------------------------------------
// kNN: packed u32 (dist|idx) keys, f32 cancellation-free distances,
// 2-way candidate split; merge via LDS. Grid = 2*NBATCH blocks of 256 thr.
// ---------------------------------------------------------------------------
__global__ __launch_bounds__(256) void knn_kernel(const float* __restrict__ points,
                                                  int* __restrict__ idx_out) {
    const int bb = blockIdx.x >> 1;
    const int qbase = (blockIdx.x & 1) * 128;
    const int t = threadIdx.x;
    const int qt = t & 127;
    const int half = t >> 7;
    const int p = qbase + qt;            // my query (within batch)

    __shared__ __align__(16) float4 sp[NP];
    __shared__ unsigned sk[128][17];

    const float* pb = points + (size_t)bb * NP * 3;
    sp[t] = make_float4(pb[t * 3 + 0], pb[t * 3 + 1], pb[t * 3 + 2], 0.f);
    __syncthreads();

    const float4 qp = sp[p];
    unsigned bk[KNN];
#pragma unroll
    for (int i = 0; i < KNN; ++i) bk[i] = 0xFFFFFFFFu;

    const int cbase = half * 128;        // wave-uniform
#pragma unroll 4
    for (int c = 0; c < 128; ++c) {
        const int cand = cbase + c;
        const float4 P = sp[cand];       // wave-uniform addr -> LDS broadcast
        const float dx = qp.x - P.x, dy = qp.y - P.y, dz = qp.z - P.z;
        const float d = fmaf(dx, dx, fmaf(dy, dy, dz * dz));
        unsigned key = (__float_as_uint(d) & 0xFFFFFF00u) | (unsigned)cand;
        key = (cand == p) ? 0xFFFFFFFFu : key;   // self-exclusion, branchless
        INSERTK(key);
    }

    if (half == 1) {
#pragma unroll
        for (int i = 0; i < KNN; ++i) sk[qt][i] = bk[i];
    }
    __syncthreads();
    if (half == 0) {
        for (int j = 0; j < KNN; ++j) {
            const unsigned key = sk[qt][j];
            if (key >= bk[KNN - 1]) break;   // ascending -> rest can't qualify
            INSERTK(key);
        }
        int* op = idx_out + ((size_t)bb * NP + p) * KNN;
#pragma unroll
        for (int i = 0; i < KNN; ++i) op[i] = (int)(bk[i] & 0xFFu);
    }
}

// ---------------------------------------------------------------------------
// Prep (unchanged): lay out weights in MFMA B-fragment order + fold BN params.
// B-frag (16x16x32): lane l holds B[ks*32 + (l>>4)*8 + j][t*16 + (l&15)].
// ---------------------------------------------------------------------------
__global__ __launch_bounds__(256) void prep_kernel(
    const float* __restrict__ w0, const float* __restrict__ w1,
    const float* __restrict__ w2, const float* __restrict__ sc_w,
    const float* __restrict__ gammas, const float* __restrict__ betas,
    const float* __restrict__ means, const float* __restrict__ variances,
    const float* __restrict__ sc_gamma, const float* __restrict__ sc_beta,
    const float* __restrict__ sc_mean, const float* __restrict__ sc_var,
    unsigned short* __restrict__ wsf, float* __restrict__ bnp)
{
    const int tid = blockIdx.x * 256 + threadIdx.x;
    if (tid < 20480) {
        const float* src;
        int base;
        if (tid < 8192)       { src = w0;   base = 0; }
        else if (tid < 12288) { src = w1;   base = 8192; }
        else if (tid < 16384) { src = w2;   base = 12288; }
        else                  { src = sc_w; base = 16384; }
        const int e2 = tid - base;
        const int f = e2 >> 9;
        const int r = e2 & 511;
        const int lane = r >> 3, j = r & 7;
        const int ks = f >> 2, t = f & 3;
        const int row = ks * 32 + (lane >> 4) * 8 + j;
        const int col = t * 16 + (lane & 15);
        wsf[tid] = f2bfu(src[row * 64 + col]);
    } else {
        const int e = tid - 20480;
        if (e < 192) {
            float s = gammas[e] * rsqrtf(variances[e] + EPSV);
            bnp[e] = s;
            bnp[192 + e] = betas[e] - means[e] * s;
        } else if (e < 256) {
            const int d = e - 192;
            float s = sc_gamma[d] * rsqrtf(sc_var[d] + EPSV);
            bnp[384 + d] = s;
            bnp[448 + d] = sc_beta[d] - sc_mean[d] * s;
        }
    }
}

// ---------------------------------------------------------------------------
// Edge MLP on matrix cores. One wave per block; wave owns 8 points
// -> 4096 blocks. __launch_bounds__(64,2): R5's (64,4) clamped VGPR to 64 and
// spilled the 128-VGPR weight set to scratch (FETCH 347MB) — (64,2) lets the
// allocator use ~120 VGPR, which still permits 4 waves/SIMD (steps at 128).
// XCD-swizzled blockIdx so each batch's 32 blocks share one XCD's L2.
// ---------------------------------------------------------------------------
__global__ __launch_bounds__(64, 2) void edge_kernel(
    const float* __restrict__ features, const int* __restrict__ knn_idx,
    const unsigned short* __restrict__ wsf, const float* __restrict__ bnp,
    float* __restrict__ out)
{
    __shared__ __align__(16) unsigned short slabA[16 * 72];  // row stride 144 B
    __shared__ __align__(16) unsigned short slabB[16 * 72];
    __shared__ float ftsbuf[8][64];   // [point q][channel]

    const int l = threadIdx.x;
    const int i = l & 15;
    const int h = l >> 4;
    // bijective XCD swizzle: 4096 blocks = 8 XCDs x 512 contiguous work items
    const int wg = (blockIdx.x & 7) * 512 + (blockIdx.x >> 3);
    const int p0 = wg * 8;
    const int b = p0 >> 8;

    const bf16x8* __restrict__ W0 = (const bf16x8*)(wsf);
    const bf16x8* __restrict__ W1 = (const bf16x8*)(wsf + 8192);
    const bf16x8* __restrict__ W2 = (const bf16x8*)(wsf + 12288);

    // layer weights resident in registers for the whole wave lifetime
    bf16x8 w0r[4][4], w1r[2][4], w2r[2][4];
#pragma unroll
    for (int ks = 0; ks < 4; ++ks)
#pragma unroll
        for (int t = 0; t < 4; ++t) w0r[ks][t] = W0[(ks * 4 + t) * 64 + l];
#pragma unroll
    for (int ks = 0; ks < 2; ++ks)
#pragma unroll
        for (int t = 0; t < 4; ++t) {
            w1r[ks][t] = W1[(ks * 4 + t) * 64 + l];
            w2r[ks][t] = W2[(ks * 4 + t) * 64 + l];
        }

    float scl[3][4], shf[3][4];
#pragma unroll
    for (int L = 0; L < 3; ++L)
#pragma unroll
        for (int t = 0; t < 4; ++t) {
            scl[L][t] = bnp[L * 64 + t * 16 + i];
            shf[L][t] = bnp[192 + L * 64 + t * 16 + i];
        }

    // preload this wave's 8 neighbor indices (lane's k = i)
    int nks[8];
#pragma unroll
    for (int q = 0; q < 8; ++q) nks[q] = knn_idx[(size_t)(p0 + q) * KNN + i];

    for (int q = 0; q < 8; ++q) {
        const float* cp = features + (size_t)(p0 + q) * NC;
        const float* sp = features + (size_t)(b * NP + nks[q]) * NC;
        float4 c0 = *(const float4*)(cp + h * 8);
        float4 c1 = *(const float4*)(cp + h * 8 + 4);
        float4 c2 = *(const float4*)(cp + 32 + h * 8);
        float4 c3 = *(const float4*)(cp + 32 + h * 8 + 4);
        float4 n0 = *(const float4*)(sp + h * 8);
        float4 n1 = *(const float4*)(sp + h * 8 + 4);
        float4 n2 = *(const float4*)(sp + 32 + h * 8);
        float4 n3 = *(const float4*)(sp + 32 + h * 8 + 4);
        float4 d0, d1, d2, d3;
        d0.x = n0.x - c0.x; d0.y = n0.y - c0.y; d0.z = n0.z - c0.z; d0.w = n0.w - c0.w;
        d1.x = n1.x - c1.x; d1.y = n1.y - c1.y; d1.z = n1.z - c1.z; d1.w = n1.w - c1.w;
        d2.x = n2.x - c2.x; d2.y = n2.y - c2.y; d2.z = n2.z - c2.z; d2.w = n2.w - c2.w;
        d3.x = n3.x - c3.x; d3.y = n3.y - c3.y; d3.z = n3.z - c3.z; d3.w = n3.w - c3.w;
        bf16x8 fA[4];
        fA[0] = pack8(c0, c1);  // A cols 0..63  = center
        fA[1] = pack8(c2, c3);
        fA[2] = pack8(d0, d1);  // A cols 64..127 = nbr - center
        fA[3] = pack8(d2, d3);

        // ---- layer 1 -> slabA ----
#pragma unroll
        for (int t = 0; t < 4; ++t) {
            f32x4 acc = {0.f, 0.f, 0.f, 0.f};
#pragma unroll
            for (int ks = 0; ks < 4; ++ks) acc = mfma16(fA[ks], w0r[ks][t], acc);
#pragma unroll
            for (int r = 0; r < 4; ++r) {
                float y = fmaxf(fmaf(acc[r], scl[0][t], shf[0][t]), 0.f);
                slabA[(h * 4 + r) * 72 + t * 16 + i] = f2bfu(y);
            }
        }
        LDS_FENCE();

        // ---- layer 2 -> slabB ----
        bf16x8 a20 = *(const bf16x8*)(slabA + i * 72 + h * 8);
        bf16x8 a21 = *(const bf16x8*)(slabA + i * 72 + h * 8 + 32);
#pragma unroll
        for (int t = 0; t < 4; ++t) {
            f32x4 acc = {0.f, 0.f, 0.f, 0.f};
            acc = mfma16(a20, w1r[0][t], acc);
            acc = mfma16(a21, w1r[1][t], acc);
#pragma unroll
            for (int r = 0; r < 4; ++r) {
                float y = fmaxf(fmaf(acc[r], scl[1][t], shf[1][t]), 0.f);
                slabB[(h * 4 + r) * 72 + t * 16 + i] = f2bfu(y);
            }
        }
        LDS_FENCE();

        // ---- layer 3 -> fts (mean over k) ----
        bf16x8 a30 = *(const bf16x8*)(slabB + i * 72 + h * 8);
        bf16x8 a31 = *(const bf16x8*)(slabB + i * 72 + h * 8 + 32);
#pragma unroll
        for (int t = 0; t < 4; ++t) {
            f32x4 acc = {0.f, 0.f, 0.f, 0.f};
            acc = mfma16(a30, w2r[0][t], acc);
            acc = mfma16(a31, w2r[1][t], acc);
            float s = 0.f;
#pragma unroll
            for (int r = 0; r < 4; ++r)
                s += fmaxf(fmaf(acc[r], scl[2][t], shf[2][t]), 0.f);
            s += __shfl_xor(s, 16, 64);  // reduce over h-groups (same i)
            s += __shfl_xor(s, 32, 64);
            if (h == 0) ftsbuf[q][t * 16 + i] = s * (1.f / 16.f);
        }
        LDS_FENCE();  // covers slab WAR for next iter + ftsbuf visibility
    }

    // ---- shortcut GEMM + epilogue: rows 0..7 = this wave's 8 points ----
    {
        const bf16x8* __restrict__ WS = (const bf16x8*)(wsf + 16384);
        float sscl[4], sshf[4];
#pragma unroll
        for (int t = 0; t < 4; ++t) {
            sscl[t] = bnp[384 + t * 16 + i];
            sshf[t] = bnp[448 + t * 16 + i];
        }
        const float* fp = features + (size_t)(p0 + (i & 7)) * NC;  // rows 8..15 dup
        float4 c0 = *(const float4*)(fp + h * 8);
        float4 c1 = *(const float4*)(fp + h * 8 + 4);
        float4 c2 = *(const float4*)(fp + 32 + h * 8);
        float4 c3 = *(const float4*)(fp + 32 + h * 8 + 4);
        bf16x8 a0 = pack8(c0, c1), a1 = pack8(c2, c3);
#pragma unroll
        for (int t = 0; t < 4; ++t) {
            f32x4 acc = {0.f, 0.f, 0.f, 0.f};
            acc = mfma16(a0, WS[t * 64 + l], acc);
            acc = mfma16(a1, WS[(4 + t) * 64 + l], acc);
            if (h < 2) {   // C rows 0..7 = real points; 8..15 are duplicates
#pragma unroll
                for (int r = 0; r < 4; ++r) {
                    const int q = h * 4 + r;
                    out[(size_t)(p0 + q) * NC + t * 16 + i] =
                        fmaxf(fmaf(acc[r], sscl[t], sshf[t]) + ftsbuf[q][t * 16 + i], 0.f);
                }
            }
        }
    }
}

extern "C" void kernel_launch(void* const* d_in, const int* in_sizes, int n_in,
                              void* d_out, int out_size, void* d_ws, size_t ws_size,
                              hipStream_t stream) {
    const float* points    = (const float*)d_in[0];
    const float* features  = (const float*)d_in[1];
    const float* w0        = (const float*)d_in[2];
    const float* w1        = (const float*)d_in[3];
    const float* w2        = (const float*)d_in[4];
    const float* gammas    = (const float*)d_in[5];
    const float* betas     = (const float*)d_in[6];
    const float* means     = (const float*)d_in[7];
    const float* variances = (const float*)d_in[8];
    const float* sc_w      = (const float*)d_in[9];
    const float* sc_gamma  = (const float*)d_in[10];
    const float* sc_beta   = (const float*)d_in[11];
    const float* sc_mean   = (const float*)d_in[12];
    const float* sc_var    = (const float*)d_in[13];
    float* out = (float*)d_out;

    int* knn_buf = (int*)d_ws;                                        // 2 MB
    unsigned short* wsf = (unsigned short*)((char*)d_ws + (1 << 21)); // 40 KB
    float* bnp = (float*)((char*)d_ws + (1 << 21) + 40960);           // 1.8 KB

    prep_kernel<<<81, 256, 0, stream>>>(w0, w1, w2, sc_w, gammas, betas, means,
                                        variances, sc_gamma, sc_beta, sc_mean,
                                        sc_var, wsf, bnp);
    knn_kernel<<<NBATCH * 2, 256, 0, stream>>>(points, knn_buf);
    edge_kernel<<<NBATCH * NP / 8, 64, 0, stream>>>(features, knn_buf, wsf, bnp, out);
}